// Round 5
// baseline (235.057 us; speedup 1.0000x reference)
//
#include <hip/hip_runtime.h>

#define D 512
#define E 8
#define H 128
#define BM 64
#define HP 136   // padded LDS row stride for h (shorts)

typedef __attribute__((ext_vector_type(8))) short short8v;
typedef __attribute__((ext_vector_type(4))) short short4v;
typedef __attribute__((ext_vector_type(4))) float float4v;

__device__ inline short f2bf(float f) {
  union { float f; unsigned u; } v; v.f = f;
  unsigned r = v.u + 0x7fffu + ((v.u >> 16) & 1u);   // RNE
  return (short)(r >> 16);
}
__device__ inline float bf2f(short s) {
  union { unsigned u; float f; } v;
  v.u = ((unsigned)(unsigned short)s) << 16;
  return v.f;
}

// ---------------- K1: router — one wave per token; also emits bf16 x and chunk counts ----------------
__global__ void k_router(const float* __restrict__ x, const float* __restrict__ Wr,
                         const float* __restrict__ br, int* __restrict__ tokE,
                         float* __restrict__ confPart, short* __restrict__ xb,
                         int* __restrict__ chunkCnt) {
  const int lane = threadIdx.x & 63;
  const int wave = threadIdx.x >> 6;
  const int token = blockIdx.x * 4 + wave;

  float wr[8][8];
  const float4* wrp = reinterpret_cast<const float4*>(Wr) + lane * 16;
#pragma unroll
  for (int j = 0; j < 8; ++j) {
    float4 a = wrp[j * 2 + 0];
    float4 b = wrp[j * 2 + 1];
    wr[j][0] = a.x; wr[j][1] = a.y; wr[j][2] = a.z; wr[j][3] = a.w;
    wr[j][4] = b.x; wr[j][5] = b.y; wr[j][6] = b.z; wr[j][7] = b.w;
  }

  const float4* xp = reinterpret_cast<const float4*>(x + (size_t)token * D + lane * 8);
  float4 x0 = xp[0], x1 = xp[1];
  float xv[8] = {x0.x, x0.y, x0.z, x0.w, x1.x, x1.y, x1.z, x1.w};

  if (xb) {   // bf16 mirror of x, coalesced 16B/lane
    short8v p;
#pragma unroll
    for (int j = 0; j < 8; ++j) p[j] = f2bf(xv[j]);
    *(short8v*)(xb + (size_t)token * D + lane * 8) = p;
  }

  float acc[E] = {0, 0, 0, 0, 0, 0, 0, 0};
#pragma unroll
  for (int j = 0; j < 8; ++j)
#pragma unroll
    for (int e = 0; e < E; ++e)
      acc[e] += xv[j] * wr[j][e];

#pragma unroll
  for (int m = 1; m < 64; m <<= 1)
#pragma unroll
    for (int e = 0; e < E; ++e)
      acc[e] += __shfl_xor(acc[e], m, 64);

  __shared__ float cf[4];
  if (lane == 0) {
#pragma unroll
    for (int e = 0; e < E; ++e) acc[e] += br[e];
    int e0 = 0; float v0 = acc[0];
#pragma unroll
    for (int e = 1; e < E; ++e) if (acc[e] > v0) { v0 = acc[e]; e0 = e; }
    int e1 = -1; float v1 = -1e30f;
#pragma unroll
    for (int e = 0; e < E; ++e) if (e != e0 && acc[e] > v1) { v1 = acc[e]; e1 = e; }
    tokE[token * 2 + 0] = e0;
    tokE[token * 2 + 1] = e1;
    int ch = token >> 8;
    atomicAdd(&chunkCnt[ch * E + e0], 1);
    atomicAdd(&chunkCnt[ch * E + e1], 1);
    cf[wave] = v0;
  }
  __syncthreads();
  if (threadIdx.x == 0) confPart[blockIdx.x] = cf[0] + cf[1] + cf[2] + cf[3];
}

// ---------------- K3: wave-parallel scan (512 thr, wave e = expert e) + stats ----------------
__global__ void k_scan(const int* __restrict__ chunkCnt, const float* __restrict__ confPart,
                       int* __restrict__ chunkOff, int* __restrict__ kept,
                       float* __restrict__ outTail, int nConf, int cap, int nTok) {
  const int lane = threadIdx.x & 63;
  const int e = threadIdx.x >> 6;         // 8 waves, one per expert (nChunks == 128)
  __shared__ int keptS[E];

  int v0 = chunkCnt[lane * E + e];
  int v1 = chunkCnt[(64 + lane) * E + e];
  int s0 = v0, s1 = v1;
#pragma unroll
  for (int off = 1; off < 64; off <<= 1) {
    int t0 = __shfl_up(s0, off, 64);
    int t1 = __shfl_up(s1, off, 64);
    if (lane >= off) { s0 += t0; s1 += t1; }
  }
  int tot0 = __shfl(s0, 63, 64);
  int total = tot0 + __shfl(s1, 63, 64);
  chunkOff[lane * E + e] = s0 - v0;
  chunkOff[(64 + lane) * E + e] = tot0 + s1 - v1;
  if (lane == 0) {
    int k = min(total, cap);
    kept[e] = k;
    keptS[e] = k;
  }

  __shared__ float s[512];
  float a = 0.f;
  for (int i = threadIdx.x; i < nConf; i += 512) a += confPart[i];
  s[threadIdx.x] = a;
  __syncthreads();
  for (int st = 256; st > 0; st >>= 1) {
    if (threadIdx.x < st) s[threadIdx.x] += s[threadIdx.x + st];
    __syncthreads();
  }
  if (threadIdx.x == 0) {
    float tot = 0.f, ld[E];
    for (int i = 0; i < E; ++i) { ld[i] = (float)keptS[i]; tot += ld[i]; }
    float denom = tot + 1e-8f;
    float loss = 0.f;
    for (int i = 0; i < E; ++i) {
      float dist = ld[i] / denom;
      loss += dist * logf(dist + 1e-8f);
      outTail[1 + i] = dist;
    }
    outTail[0] = loss;
    outTail[1 + E] = s[0] / (float)nTok;
  }
}

// ---------------- K4: rank assignment + dispatch lists + token->slot map ----------------
__global__ void k_dispatch(const int* __restrict__ tokE, const int* __restrict__ chunkOff,
                           int* __restrict__ expList, int2* __restrict__ tokSlot, int cap) {
  const int lane = threadIdx.x & 63;
  const int wave = threadIdx.x >> 6;
  const int token = blockIdx.x * 256 + threadIdx.x;
  const int e0 = tokE[token * 2 + 0];
  const int e1 = tokE[token * 2 + 1];
  __shared__ int wcnt[4][E];
  unsigned long long lt = (lane == 63) ? 0x7fffffffffffffffull : ((1ull << lane) - 1ull);
  int r0 = 0, r1 = 0;
#pragma unroll
  for (int e = 0; e < E; ++e) {
    unsigned long long b0 = __ballot(e0 == e);
    unsigned long long b1 = __ballot(e1 == e);
    unsigned long long m = b0 | b1;
    if (e0 == e) r0 = __popcll(m & lt);
    if (e1 == e) r1 = __popcll(m & lt);
    if (lane == 0) wcnt[wave][e] = __popcll(m);
  }
  __syncthreads();
  int base0 = chunkOff[blockIdx.x * E + e0];
  int base1 = chunkOff[blockIdx.x * E + e1];
  for (int w = 0; w < wave; ++w) {
    base0 += wcnt[w][e0];
    base1 += wcnt[w][e1];
  }
  int g0 = base0 + r0;
  int g1 = base1 + r1;
  if (g0 < cap) expList[e0 * cap + g0] = token;
  if (g1 < cap) expList[e1 * cap + g1] = token;
  tokSlot[token] = make_int2(g0 < cap ? e0 * cap + g0 : -1,
                             g1 < cap ? e1 * cap + g1 : -1);
}

// ---------------- K-cvt: fp32 [E][R][C] -> bf16 transposed [E][C][R] ----------------
__global__ void k_transpose(const float* __restrict__ in, short* __restrict__ outT,
                            int R, int C) {
  __shared__ float t[32][33];
  const int e = blockIdx.z;
  const int c0 = blockIdx.x * 32, r0 = blockIdx.y * 32;
  const int lx = threadIdx.x & 31, ly = threadIdx.x >> 5;
  const float* p = in + ((size_t)e * R + r0) * C + c0;
#pragma unroll
  for (int i = 0; i < 32; i += 8) t[ly + i][lx] = p[(size_t)(ly + i) * C + lx];
  __syncthreads();
  short* q = outT + ((size_t)e * C + c0) * R + r0;
#pragma unroll
  for (int i = 0; i < 32; i += 8) q[(size_t)(ly + i) * R + lx] = f2bf(t[lx][ly + i]);
}

// ---------------- K5: per-expert FFN via MFMA (swapped operands), bf16 y scratch ----------------
// USE_XB: gather x from bf16 mirror (16B/lane, no cvt). Fallback: fp32 + cvt.
template <bool USE_XB>
__global__ __launch_bounds__(256, 1) void k_expert_mfma(
    const short* __restrict__ xb, const float* __restrict__ x,
    const short* __restrict__ W1t, const float* __restrict__ b1,
    const short* __restrict__ W2t, const float* __restrict__ b2,
    const int* __restrict__ expList, const int* __restrict__ kept,
    short* __restrict__ yscr, int cap) {
  const int e = blockIdx.y;
  const int cnt = kept[e];
  const int t0 = blockIdx.x * BM;
  if (t0 >= cnt) return;
  const int lane = threadIdx.x & 63;
  const int wave = threadIdx.x >> 6;
  const int rb = wave * 16;
  const int n15 = lane & 15;          // token index within wave tile (B-frag n)
  const int grp = lane >> 4;          // k sub-group
  const int kg = grp * 8;

  __shared__ int toks[BM];
  __shared__ short hs[BM][HP];

  if (threadIdx.x < BM) {
    int idx = min(t0 + (int)threadIdx.x, cnt - 1);
    toks[threadIdx.x] = expList[e * cap + idx];
  }
  __syncthreads();

  // ---- load all 16 x K-fragments up front (independent 16B loads) ----
  short8v xf[16];
  if (USE_XB) {
    const short* xrow = xb + (size_t)toks[rb + n15] * D + kg;
#pragma unroll
    for (int ks = 0; ks < 16; ++ks)
      xf[ks] = *(const short8v*)(xrow + ks * 32);
  } else {
    const float* xrow = x + (size_t)toks[rb + n15] * D + kg;
#pragma unroll
    for (int ks = 0; ks < 16; ++ks) {
      float4 a = *(const float4*)(xrow + ks * 32);
      float4 b = *(const float4*)(xrow + ks * 32 + 4);
      short8v f;
      f[0] = f2bf(a.x); f[1] = f2bf(a.y); f[2] = f2bf(a.z); f[3] = f2bf(a.w);
      f[4] = f2bf(b.x); f[5] = f2bf(b.y); f[6] = f2bf(b.z); f[7] = f2bf(b.w);
      xf[ks] = f;
    }
  }

  // ---- layer 1: A = W1 rows (hcol m), B = x (token n), 8 m-tiles ----
  const short* w1p = W1t + ((size_t)e * H + n15) * D + kg;
  float4v acc[8];
#pragma unroll
  for (int t = 0; t < 8; ++t) acc[t] = (float4v){0.f, 0.f, 0.f, 0.f};
#pragma unroll
  for (int ks = 0; ks < 16; ++ks) {
#pragma unroll
    for (int t = 0; t < 8; ++t) {
      short8v a = *(const short8v*)(w1p + (size_t)t * 16 * D + ks * 32);
      acc[t] = __builtin_amdgcn_mfma_f32_16x16x32_bf16(a, xf[ks], acc[t], 0, 0, 0);
    }
  }
#pragma unroll
  for (int t = 0; t < 8; ++t) {
    float4 bb = *(const float4*)(b1 + e * H + t * 16 + grp * 4);
    short4v p;
    p[0] = f2bf(fmaxf(acc[t][0] + bb.x, 0.f));
    p[1] = f2bf(fmaxf(acc[t][1] + bb.y, 0.f));
    p[2] = f2bf(fmaxf(acc[t][2] + bb.z, 0.f));
    p[3] = f2bf(fmaxf(acc[t][3] + bb.w, 0.f));
    *(short4v*)(&hs[rb + n15][t * 16 + grp * 4]) = p;
  }
  __syncthreads();

  // ---- layer 2: A = W2 rows (dcol m), B = h frags from LDS ----
  short8v a4[4];
#pragma unroll
  for (int ks = 0; ks < 4; ++ks)
    a4[ks] = *(const short8v*)(&hs[rb + n15][ks * 32 + kg]);

  const short* w2p = W2t + ((size_t)e * D + n15) * H + kg;
  short* yrow = yscr + ((size_t)(e * cap + t0 + rb + n15)) * D;
#pragma unroll 8
  for (int t = 0; t < 32; ++t) {
    float4v y = (float4v){0.f, 0.f, 0.f, 0.f};
#pragma unroll
    for (int ks = 0; ks < 4; ++ks) {
      short8v a = *(const short8v*)(w2p + (size_t)t * 16 * H + ks * 32);
      y = __builtin_amdgcn_mfma_f32_16x16x32_bf16(a, a4[ks], y, 0, 0, 0);
    }
    float4 bb = *(const float4*)(b2 + e * D + t * 16 + grp * 4);
    short4v p;
    p[0] = f2bf(y[0] + bb.x);
    p[1] = f2bf(y[1] + bb.y);
    p[2] = f2bf(y[2] + bb.z);
    p[3] = f2bf(y[3] + bb.w);
    *(short4v*)(yrow + t * 16 + grp * 4) = p;
  }
}

// ---------------- K6: combine — out[token] = sum of kept slots (or 0) ----------------
__global__ void k_combine(const short* __restrict__ yscr, const int2* __restrict__ tokSlot,
                          float* __restrict__ out) {
  const int idx = blockIdx.x * 256 + threadIdx.x;   // one float4 per thread
  const int token = idx >> 7;                       // 128 float4 per row
  const int c4 = idx & 127;
  int2 sl = tokSlot[token];
  float4 r = make_float4(0.f, 0.f, 0.f, 0.f);
  if (sl.x >= 0) {
    short4v y = *(const short4v*)(yscr + (size_t)sl.x * D + c4 * 4);
    r.x += bf2f(y[0]); r.y += bf2f(y[1]); r.z += bf2f(y[2]); r.w += bf2f(y[3]);
  }
  if (sl.y >= 0) {
    short4v y = *(const short4v*)(yscr + (size_t)sl.y * D + c4 * 4);
    r.x += bf2f(y[0]); r.y += bf2f(y[1]); r.z += bf2f(y[2]); r.w += bf2f(y[3]);
  }
  reinterpret_cast<float4*>(out)[idx] = r;
}

extern "C" void kernel_launch(void* const* d_in, const int* in_sizes, int n_in,
                              void* d_out, int out_size, void* d_ws, size_t ws_size,
                              hipStream_t stream) {
  const float* x  = (const float*)d_in[0];
  const float* Wr = (const float*)d_in[1];
  const float* br = (const float*)d_in[2];
  const float* W1 = (const float*)d_in[3];
  const float* b1 = (const float*)d_in[4];
  const float* W2 = (const float*)d_in[5];
  const float* b2 = (const float*)d_in[6];
  float* out = (float*)d_out;

  const int N = in_sizes[0] / D;                 // 32768
  const int cap = (int)(1.25f * (float)(N / E)); // 5120
  const int chunks = N / 256;                    // 128

  int* tokE = (int*)d_ws;                                    // N*2
  float* confPart = (float*)(tokE + (size_t)N * 2);          // N/4
  int* chunkCnt = (int*)(confPart + N / 4);                  // chunks*E
  int* chunkOff = chunkCnt + chunks * E;                     // chunks*E
  int* kept = chunkOff + chunks * E;                         // E
  int2* tokSlot = (int2*)(kept + E);                         // N int2
  int* expList = (int*)(tokSlot + N);                        // E*cap
  short* W1t = (short*)(expList + (size_t)E * cap);          // [E][H][D]
  short* W2t = W1t + (size_t)E * H * D;                      // [E][D][H]
  short* yscr = W2t + (size_t)E * H * D;                     // [E*cap][D] bf16
  short* xb = yscr + (size_t)E * cap * D;                    // [N][D] bf16 (optional)

  const size_t needed = (size_t)((char*)(xb + (size_t)N * D) - (char*)d_ws);
  const bool useXB = ws_size >= needed;

  (void)hipMemsetAsync(chunkCnt, 0, (size_t)chunks * E * sizeof(int), stream);

  k_transpose<<<dim3(H / 32, D / 32, E), 256, 0, stream>>>(W1, W1t, D, H);
  k_transpose<<<dim3(D / 32, H / 32, E), 256, 0, stream>>>(W2, W2t, H, D);

  k_router<<<N / 4, 256, 0, stream>>>(x, Wr, br, tokE, confPart,
                                      useXB ? xb : nullptr, chunkCnt);
  k_scan<<<1, 512, 0, stream>>>(chunkCnt, confPart, chunkOff, kept,
                                out + (size_t)N * D, N / 4, cap, N);
  k_dispatch<<<chunks, 256, 0, stream>>>(tokE, chunkOff, expList, tokSlot, cap);

  const int tiles = (cap + BM - 1) / BM;
  dim3 g5(tiles, E);
  if (useXB)
    k_expert_mfma<true><<<g5, 256, 0, stream>>>(xb, x, W1t, b1, W2t, b2,
                                                expList, kept, yscr, cap);
  else
    k_expert_mfma<false><<<g5, 256, 0, stream>>>(nullptr, x, W1t, b1, W2t, b2,
                                                 expList, kept, yscr, cap);

  k_combine<<<(N * D / 4) / 256, 256, 0, stream>>>(yscr, tokSlot, out);
}

// Round 6
// 157.724 us; speedup vs baseline: 1.4903x; 1.4903x over previous
//
#include <hip/hip_runtime.h>

#define D 512
#define E 8
#define H 128
#define BM 64
#define HP 136   // padded LDS row stride for h (shorts)

typedef __attribute__((ext_vector_type(8))) short short8v;
typedef __attribute__((ext_vector_type(4))) short short4v;
typedef __attribute__((ext_vector_type(4))) float float4v;

__device__ inline short f2bf(float f) {
  union { float f; unsigned u; } v; v.f = f;
  unsigned r = v.u + 0x7fffu + ((v.u >> 16) & 1u);   // RNE
  return (short)(r >> 16);
}
__device__ inline float bf2f(short s) {
  union { unsigned u; float f; } v;
  v.u = ((unsigned)(unsigned short)s) << 16;
  return v.f;
}

// ---------------- K0: swizzle weights into MFMA fragment-contiguous bf16 ----------------
// W1f[e][f=ks*8+t][lane][j]  (ks 0..15, t 0..7)   A-elem: row=t*16+(l&15), k=ks*32+(l>>4)*8+j
// W2f[e][f=ks*32+t][lane][j] (ks 0..3,  t 0..31)  A-elem: row=t*16+(l&15), k=ks*32+(l>>4)*8+j
__global__ void k_swizzle(const float* __restrict__ W1, const float* __restrict__ W2,
                          short* __restrict__ W1f, short* __restrict__ W2f) {
  const int e = blockIdx.y;
  const int lane = threadIdx.x & 63;
  const int wv = threadIdx.x >> 6;
  const int r = lane & 15, g = lane >> 4;
  if (blockIdx.x == 0) {
    // W1: [E][D][H]
    for (int f = wv * 32; f < wv * 32 + 32; ++f) {
      int ks = f >> 3, t = f & 7;
      const float* src = W1 + ((size_t)e * D + ks * 32 + g * 8) * H + t * 16 + r;
      short8v o;
#pragma unroll
      for (int j = 0; j < 8; ++j) o[j] = f2bf(src[(size_t)j * H]);
      *(short8v*)(W1f + (((size_t)e * 128 + f) * 64 + lane) * 8) = o;
    }
  } else {
    // W2: [E][H][D]
    for (int f = wv * 32; f < wv * 32 + 32; ++f) {
      int ks = f >> 5, t = f & 31;
      const float* src = W2 + ((size_t)e * H + ks * 32 + g * 8) * D + t * 16 + r;
      short8v o;
#pragma unroll
      for (int j = 0; j < 8; ++j) o[j] = f2bf(src[(size_t)j * D]);
      *(short8v*)(W2f + (((size_t)e * 128 + f) * 64 + lane) * 8) = o;
    }
  }
}

// ---------------- K1: router — one wave per token; also emits bf16 x ----------------
__global__ void k_router(const float* __restrict__ x, const float* __restrict__ Wr,
                         const float* __restrict__ br, int* __restrict__ tokE,
                         float* __restrict__ confPart, short* __restrict__ xb) {
  const int lane = threadIdx.x & 63;
  const int wave = threadIdx.x >> 6;
  const int token = blockIdx.x * 4 + wave;

  float wr[8][8];
  const float4* wrp = reinterpret_cast<const float4*>(Wr) + lane * 16;
#pragma unroll
  for (int j = 0; j < 8; ++j) {
    float4 a = wrp[j * 2 + 0];
    float4 b = wrp[j * 2 + 1];
    wr[j][0] = a.x; wr[j][1] = a.y; wr[j][2] = a.z; wr[j][3] = a.w;
    wr[j][4] = b.x; wr[j][5] = b.y; wr[j][6] = b.z; wr[j][7] = b.w;
  }

  const float4* xp = reinterpret_cast<const float4*>(x + (size_t)token * D + lane * 8);
  float4 x0 = xp[0], x1 = xp[1];
  float xv[8] = {x0.x, x0.y, x0.z, x0.w, x1.x, x1.y, x1.z, x1.w};

  if (xb) {   // bf16 mirror of x, coalesced 16B/lane
    short8v p;
#pragma unroll
    for (int j = 0; j < 8; ++j) p[j] = f2bf(xv[j]);
    *(short8v*)(xb + (size_t)token * D + lane * 8) = p;
  }

  float acc[E] = {0, 0, 0, 0, 0, 0, 0, 0};
#pragma unroll
  for (int j = 0; j < 8; ++j)
#pragma unroll
    for (int e = 0; e < E; ++e)
      acc[e] += xv[j] * wr[j][e];

#pragma unroll
  for (int m = 1; m < 64; m <<= 1)
#pragma unroll
    for (int e = 0; e < E; ++e)
      acc[e] += __shfl_xor(acc[e], m, 64);

  __shared__ float cf[4];
  if (lane == 0) {
#pragma unroll
    for (int e = 0; e < E; ++e) acc[e] += br[e];
    int e0 = 0; float v0 = acc[0];
#pragma unroll
    for (int e = 1; e < E; ++e) if (acc[e] > v0) { v0 = acc[e]; e0 = e; }
    int e1 = -1; float v1 = -1e30f;
#pragma unroll
    for (int e = 0; e < E; ++e) if (e != e0 && acc[e] > v1) { v1 = acc[e]; e1 = e; }
    tokE[token * 2 + 0] = e0;
    tokE[token * 2 + 1] = e1;
    cf[wave] = v0;
  }
  __syncthreads();
  if (threadIdx.x == 0) confPart[blockIdx.x] = cf[0] + cf[1] + cf[2] + cf[3];
}

// ---------------- K2: per-chunk (256 tokens) expert counts ----------------
__global__ void k_count(const int* __restrict__ tokE, int* __restrict__ chunkCnt) {
  __shared__ int c[E];
  if (threadIdx.x < E) c[threadIdx.x] = 0;
  __syncthreads();
  int token = blockIdx.x * 256 + threadIdx.x;
  atomicAdd(&c[tokE[token * 2 + 0]], 1);
  atomicAdd(&c[tokE[token * 2 + 1]], 1);
  __syncthreads();
  if (threadIdx.x < E) chunkCnt[blockIdx.x * E + threadIdx.x] = c[threadIdx.x];
}

// ---------------- K3: wave-parallel scan (512 thr, wave e = expert e) + stats ----------------
__global__ void k_scan(const int* __restrict__ chunkCnt, const float* __restrict__ confPart,
                       int* __restrict__ chunkOff, int* __restrict__ kept,
                       float* __restrict__ outTail, int nConf, int cap, int nTok) {
  const int lane = threadIdx.x & 63;
  const int e = threadIdx.x >> 6;         // 8 waves, one per expert (nChunks == 128)
  __shared__ int keptS[E];

  int v0 = chunkCnt[lane * E + e];
  int v1 = chunkCnt[(64 + lane) * E + e];
  int s0 = v0, s1 = v1;
#pragma unroll
  for (int off = 1; off < 64; off <<= 1) {
    int t0 = __shfl_up(s0, off, 64);
    int t1 = __shfl_up(s1, off, 64);
    if (lane >= off) { s0 += t0; s1 += t1; }
  }
  int tot0 = __shfl(s0, 63, 64);
  int total = tot0 + __shfl(s1, 63, 64);
  chunkOff[lane * E + e] = s0 - v0;
  chunkOff[(64 + lane) * E + e] = tot0 + s1 - v1;
  if (lane == 0) {
    int k = min(total, cap);
    kept[e] = k;
    keptS[e] = k;
  }

  __shared__ float s[512];
  float a = 0.f;
  for (int i = threadIdx.x; i < nConf; i += 512) a += confPart[i];
  s[threadIdx.x] = a;
  __syncthreads();
  for (int st = 256; st > 0; st >>= 1) {
    if (threadIdx.x < st) s[threadIdx.x] += s[threadIdx.x + st];
    __syncthreads();
  }
  if (threadIdx.x == 0) {
    float tot = 0.f, ld[E];
    for (int i = 0; i < E; ++i) { ld[i] = (float)keptS[i]; tot += ld[i]; }
    float denom = tot + 1e-8f;
    float loss = 0.f;
    for (int i = 0; i < E; ++i) {
      float dist = ld[i] / denom;
      loss += dist * logf(dist + 1e-8f);
      outTail[1 + i] = dist;
    }
    outTail[0] = loss;
    outTail[1 + E] = s[0] / (float)nTok;
  }
}

// ---------------- K4: rank assignment + dispatch lists + token->slot map ----------------
__global__ void k_dispatch(const int* __restrict__ tokE, const int* __restrict__ chunkOff,
                           int* __restrict__ expList, int2* __restrict__ tokSlot, int cap) {
  const int lane = threadIdx.x & 63;
  const int wave = threadIdx.x >> 6;
  const int token = blockIdx.x * 256 + threadIdx.x;
  const int e0 = tokE[token * 2 + 0];
  const int e1 = tokE[token * 2 + 1];
  __shared__ int wcnt[4][E];
  unsigned long long lt = (lane == 63) ? 0x7fffffffffffffffull : ((1ull << lane) - 1ull);
  int r0 = 0, r1 = 0;
#pragma unroll
  for (int e = 0; e < E; ++e) {
    unsigned long long b0 = __ballot(e0 == e);
    unsigned long long b1 = __ballot(e1 == e);
    unsigned long long m = b0 | b1;
    if (e0 == e) r0 = __popcll(m & lt);
    if (e1 == e) r1 = __popcll(m & lt);
    if (lane == 0) wcnt[wave][e] = __popcll(m);
  }
  __syncthreads();
  int base0 = chunkOff[blockIdx.x * E + e0];
  int base1 = chunkOff[blockIdx.x * E + e1];
  for (int w = 0; w < wave; ++w) {
    base0 += wcnt[w][e0];
    base1 += wcnt[w][e1];
  }
  int g0 = base0 + r0;
  int g1 = base1 + r1;
  if (g0 < cap) expList[e0 * cap + g0] = token;
  if (g1 < cap) expList[e1 * cap + g1] = token;
  tokSlot[token] = make_int2(g0 < cap ? e0 * cap + g0 : -1,
                             g1 < cap ? e1 * cap + g1 : -1);
}

// ---------------- K5: per-expert FFN via MFMA, fragment-contiguous weights ----------------
template <bool USE_XB>
__global__ __launch_bounds__(256, 1) void k_expert_mfma(
    const short* __restrict__ xb, const float* __restrict__ x,
    const short* __restrict__ W1f, const float* __restrict__ b1,
    const short* __restrict__ W2f, const float* __restrict__ b2,
    const int* __restrict__ expList, const int* __restrict__ kept,
    short* __restrict__ yscr, int cap) {
  const int e = blockIdx.y;
  const int cnt = kept[e];
  const int t0 = blockIdx.x * BM;
  if (t0 >= cnt) return;
  const int lane = threadIdx.x & 63;
  const int wave = threadIdx.x >> 6;
  const int rb = wave * 16;
  const int n15 = lane & 15;          // token within wave tile (B-frag n / C col)
  const int grp = lane >> 4;
  const int kg = grp * 8;

  __shared__ int toks[BM];
  __shared__ short hs[BM][HP];

  if (threadIdx.x < BM) {
    int idx = min(t0 + (int)threadIdx.x, cnt - 1);
    toks[threadIdx.x] = expList[e * cap + idx];
  }
  __syncthreads();

  // ---- all 16 x K-fragments up front ----
  short8v xf[16];
  if (USE_XB) {
    const short* xrow = xb + (size_t)toks[rb + n15] * D + kg;
#pragma unroll
    for (int ks = 0; ks < 16; ++ks)
      xf[ks] = *(const short8v*)(xrow + ks * 32);
  } else {
    const float* xrow = x + (size_t)toks[rb + n15] * D + kg;
#pragma unroll
    for (int ks = 0; ks < 16; ++ks) {
      float4 a = *(const float4*)(xrow + ks * 32);
      float4 b = *(const float4*)(xrow + ks * 32 + 4);
      short8v f;
      f[0] = f2bf(a.x); f[1] = f2bf(a.y); f[2] = f2bf(a.z); f[3] = f2bf(a.w);
      f[4] = f2bf(b.x); f[5] = f2bf(b.y); f[6] = f2bf(b.z); f[7] = f2bf(b.w);
      xf[ks] = f;
    }
  }

  // ---- layer 1: acc[t] over 8 hcol m-tiles; frag loads are contiguous 1KB/wave ----
  const short* w1 = W1f + ((size_t)e * 128 * 64 + lane) * 8;
  float4v acc[8];
#pragma unroll
  for (int t = 0; t < 8; ++t) acc[t] = (float4v){0.f, 0.f, 0.f, 0.f};
#pragma unroll
  for (int ks = 0; ks < 16; ++ks) {
    short8v wf[8];
#pragma unroll
    for (int t = 0; t < 8; ++t)
      wf[t] = *(const short8v*)(w1 + (size_t)(ks * 8 + t) * 64 * 8);
#pragma unroll
    for (int t = 0; t < 8; ++t)
      acc[t] = __builtin_amdgcn_mfma_f32_16x16x32_bf16(wf[t], xf[ks], acc[t], 0, 0, 0);
  }
#pragma unroll
  for (int t = 0; t < 8; ++t) {
    float4 bb = *(const float4*)(b1 + e * H + t * 16 + grp * 4);
    short4v p;
    p[0] = f2bf(fmaxf(acc[t][0] + bb.x, 0.f));
    p[1] = f2bf(fmaxf(acc[t][1] + bb.y, 0.f));
    p[2] = f2bf(fmaxf(acc[t][2] + bb.z, 0.f));
    p[3] = f2bf(fmaxf(acc[t][3] + bb.w, 0.f));
    *(short4v*)(&hs[rb + n15][t * 16 + grp * 4]) = p;
  }
  __syncthreads();

  // ---- layer 2: 32 dcol m-tiles, K = H = 128 (4 k-steps) ----
  short8v a4[4];
#pragma unroll
  for (int ks = 0; ks < 4; ++ks)
    a4[ks] = *(const short8v*)(&hs[rb + n15][ks * 32 + kg]);

  const short* w2 = W2f + ((size_t)e * 128 * 64 + lane) * 8;
  short* yrow = yscr + ((size_t)(e * cap + t0 + rb + n15)) * D;
#pragma unroll 4
  for (int t = 0; t < 32; ++t) {
    short8v wf[4];
#pragma unroll
    for (int ks = 0; ks < 4; ++ks)
      wf[ks] = *(const short8v*)(w2 + (size_t)(ks * 32 + t) * 64 * 8);
    float4v y = (float4v){0.f, 0.f, 0.f, 0.f};
#pragma unroll
    for (int ks = 0; ks < 4; ++ks)
      y = __builtin_amdgcn_mfma_f32_16x16x32_bf16(wf[ks], a4[ks], y, 0, 0, 0);
    float4 bb = *(const float4*)(b2 + e * D + t * 16 + grp * 4);
    short4v p;
    p[0] = f2bf(y[0] + bb.x);
    p[1] = f2bf(y[1] + bb.y);
    p[2] = f2bf(y[2] + bb.z);
    p[3] = f2bf(y[3] + bb.w);
    *(short4v*)(yrow + t * 16 + grp * 4) = p;
  }
}

// ---------------- K6: combine — out[token] = sum of kept slots (or 0) ----------------
__global__ void k_combine(const short* __restrict__ yscr, const int2* __restrict__ tokSlot,
                          float* __restrict__ out) {
  const int idx = blockIdx.x * 256 + threadIdx.x;   // one float4 per thread
  const int token = idx >> 7;                       // 128 float4 per row
  const int c4 = idx & 127;
  int2 sl = tokSlot[token];
  float4 r = make_float4(0.f, 0.f, 0.f, 0.f);
  if (sl.x >= 0) {
    short4v y = *(const short4v*)(yscr + (size_t)sl.x * D + c4 * 4);
    r.x += bf2f(y[0]); r.y += bf2f(y[1]); r.z += bf2f(y[2]); r.w += bf2f(y[3]);
  }
  if (sl.y >= 0) {
    short4v y = *(const short4v*)(yscr + (size_t)sl.y * D + c4 * 4);
    r.x += bf2f(y[0]); r.y += bf2f(y[1]); r.z += bf2f(y[2]); r.w += bf2f(y[3]);
  }
  reinterpret_cast<float4*>(out)[idx] = r;
}

extern "C" void kernel_launch(void* const* d_in, const int* in_sizes, int n_in,
                              void* d_out, int out_size, void* d_ws, size_t ws_size,
                              hipStream_t stream) {
  const float* x  = (const float*)d_in[0];
  const float* Wr = (const float*)d_in[1];
  const float* br = (const float*)d_in[2];
  const float* W1 = (const float*)d_in[3];
  const float* b1 = (const float*)d_in[4];
  const float* W2 = (const float*)d_in[5];
  const float* b2 = (const float*)d_in[6];
  float* out = (float*)d_out;

  const int N = in_sizes[0] / D;                 // 32768
  const int cap = (int)(1.25f * (float)(N / E)); // 5120
  const int chunks = N / 256;                    // 128

  int* tokE = (int*)d_ws;                                    // N*2
  float* confPart = (float*)(tokE + (size_t)N * 2);          // N/4
  int* chunkCnt = (int*)(confPart + N / 4);                  // chunks*E
  int* chunkOff = chunkCnt + chunks * E;                     // chunks*E
  int* kept = chunkOff + chunks * E;                         // E
  int2* tokSlot = (int2*)(kept + E);                         // N int2
  int* expList = (int*)(tokSlot + N);                        // E*cap
  short* W1f = (short*)(expList + (size_t)E * cap);          // [E][128][64][8]
  short* W2f = W1f + (size_t)E * H * D;                      // [E][128][64][8]
  short* yscr = W2f + (size_t)E * H * D;                     // [E*cap][D] bf16
  short* xb = yscr + (size_t)E * cap * D;                    // [N][D] bf16 (optional)

  const size_t needed = (size_t)((char*)(xb + (size_t)N * D) - (char*)d_ws);
  const bool useXB = ws_size >= needed;

  k_swizzle<<<dim3(2, E), 256, 0, stream>>>(W1, W2, W1f, W2f);

  k_router<<<N / 4, 256, 0, stream>>>(x, Wr, br, tokE, confPart,
                                      useXB ? xb : nullptr);
  k_count<<<chunks, 256, 0, stream>>>(tokE, chunkCnt);
  k_scan<<<1, 512, 0, stream>>>(chunkCnt, confPart, chunkOff, kept,
                                out + (size_t)N * D, N / 4, cap, N);
  k_dispatch<<<chunks, 256, 0, stream>>>(tokE, chunkOff, expList, tokSlot, cap);

  const int tiles = (cap + BM - 1) / BM;
  dim3 g5(tiles, E);
  if (useXB)
    k_expert_mfma<true><<<g5, 256, 0, stream>>>(xb, x, W1f, b1, W2f, b2,
                                                expList, kept, yscr, cap);
  else
    k_expert_mfma<false><<<g5, 256, 0, stream>>>(nullptr, x, W1f, b1, W2f, b2,
                                                 expList, kept, yscr, cap);

  k_combine<<<(N * D / 4) / 256, 256, 0, stream>>>(yscr, tokSlot, out);
}

// Round 7
// 113.848 us; speedup vs baseline: 2.0647x; 1.3854x over previous
//
#include <hip/hip_runtime.h>

#define D 512
#define E 8
#define H 128
#define BM 64
#define HP 136   // padded LDS row stride for h (shorts)
#define RT 16    // tokens per wave in router

typedef __attribute__((ext_vector_type(8))) short short8v;
typedef __attribute__((ext_vector_type(4))) short short4v;
typedef __attribute__((ext_vector_type(4))) float float4v;

__device__ inline short f2bf(float f) {
  union { float f; unsigned u; } v; v.f = f;
  unsigned r = v.u + 0x7fffu + ((v.u >> 16) & 1u);   // RNE
  return (short)(r >> 16);
}
__device__ inline float bf2f(short s) {
  union { unsigned u; float f; } v;
  v.u = ((unsigned)(unsigned short)s) << 16;
  return v.f;
}

// ---------------- K0: swizzle weights into MFMA fragment-contiguous bf16 ----------------
// W1f[e][f=ks*8+t][lane][j]  (ks 0..15, t 0..7)   A-elem: row=t*16+(l&15), k=ks*32+(l>>4)*8+j
// W2f[e][f=ks*32+t][lane][j] (ks 0..3,  t 0..31)
__global__ void k_swizzle(const float* __restrict__ W1, const float* __restrict__ W2,
                          short* __restrict__ W1f, short* __restrict__ W2f) {
  const int e = blockIdx.y;
  const int lane = threadIdx.x & 63;
  const int wv = threadIdx.x >> 6;
  const int r = lane & 15, g = lane >> 4;
  const int which = blockIdx.x >> 4;                 // 0: W1, 1: W2
  const int fbase = ((blockIdx.x & 15) * 4 + wv) * 2;
  if (which == 0) {
#pragma unroll
    for (int f = fbase; f < fbase + 2; ++f) {
      int ks = f >> 3, t = f & 7;
      const float* src = W1 + ((size_t)e * D + ks * 32 + g * 8) * H + t * 16 + r;
      short8v o;
#pragma unroll
      for (int j = 0; j < 8; ++j) o[j] = f2bf(src[(size_t)j * H]);
      *(short8v*)(W1f + (((size_t)e * 128 + f) * 64 + lane) * 8) = o;
    }
  } else {
#pragma unroll
    for (int f = fbase; f < fbase + 2; ++f) {
      int ks = f >> 5, t = f & 31;
      const float* src = W2 + ((size_t)e * H + ks * 32 + g * 8) * D + t * 16 + r;
      short8v o;
#pragma unroll
      for (int j = 0; j < 8; ++j) o[j] = f2bf(src[(size_t)j * D]);
      *(short8v*)(W2f + (((size_t)e * 128 + f) * 64 + lane) * 8) = o;
    }
  }
}

// ---------------- K1: router — one wave per 16 tokens, fold-butterfly reduce ----------------
__global__ void k_router(const float* __restrict__ x, const float* __restrict__ Wr,
                         const float* __restrict__ br, int* __restrict__ tokE,
                         float* __restrict__ confPart, short* __restrict__ xb) {
  const int lane = threadIdx.x & 63;
  const int wave = threadIdx.x >> 6;
  const int tbase = (blockIdx.x * 4 + wave) * RT;

  // Wr rows [lane*8 .. lane*8+7] in registers — loaded ONCE per wave, reused for 16 tokens
  float wr[8][8];
  const float4* wrp = reinterpret_cast<const float4*>(Wr) + lane * 16;
#pragma unroll
  for (int j = 0; j < 8; ++j) {
    float4 a = wrp[j * 2 + 0];
    float4 b = wrp[j * 2 + 1];
    wr[j][0] = a.x; wr[j][1] = a.y; wr[j][2] = a.z; wr[j][3] = a.w;
    wr[j][4] = b.x; wr[j][5] = b.y; wr[j][6] = b.z; wr[j][7] = b.w;
  }

  // expert owned by this lane after the fold stages: bit0->+4, bit1->+2, bit2->+1
  const int myE = ((lane & 1) << 2) | (lane & 2) | ((lane >> 2) & 1);
  const float brv = br[myE];

  float conf = 0.f;

#pragma unroll 2
  for (int tt = 0; tt < RT; ++tt) {
    const int token = tbase + tt;
    const float4* xp = reinterpret_cast<const float4*>(x + (size_t)token * D + lane * 8);
    float4 x0 = xp[0], x1 = xp[1];
    float xv[8] = {x0.x, x0.y, x0.z, x0.w, x1.x, x1.y, x1.z, x1.w};

    if (xb) {   // bf16 mirror of x, coalesced 16B/lane
      short8v p;
#pragma unroll
      for (int j = 0; j < 8; ++j) p[j] = f2bf(xv[j]);
      *(short8v*)(xb + (size_t)token * D + lane * 8) = p;
    }

    float v[8] = {0, 0, 0, 0, 0, 0, 0, 0};
#pragma unroll
    for (int j = 0; j < 8; ++j)
#pragma unroll
      for (int e = 0; e < E; ++e)
        v[e] += xv[j] * wr[j][e];

    // fold stage m=1: keep experts 0-3 (even lane) / 4-7 (odd lane)
#pragma unroll
    for (int i = 0; i < 4; ++i) {
      float a = v[i] + __shfl_xor(v[i], 1, 64);
      float b = v[i + 4] + __shfl_xor(v[i + 4], 1, 64);
      v[i] = (lane & 1) ? b : a;
    }
    // fold stage m=2
#pragma unroll
    for (int i = 0; i < 2; ++i) {
      float a = v[i] + __shfl_xor(v[i], 2, 64);
      float b = v[i + 2] + __shfl_xor(v[i + 2], 2, 64);
      v[i] = (lane & 2) ? b : a;
    }
    // fold stage m=4
    {
      float a = v[0] + __shfl_xor(v[0], 4, 64);
      float b = v[1] + __shfl_xor(v[1], 4, 64);
      v[0] = (lane & 4) ? b : a;
    }
    // full-sum stages
    v[0] += __shfl_xor(v[0], 8, 64);
    v[0] += __shfl_xor(v[0], 16, 64);
    v[0] += __shfl_xor(v[0], 32, 64);

    const float logit = v[0] + brv;

    // top-1 over the 8-lane expert group (ties -> lower index, matching top_k)
    float m1 = logit; int i1 = myE;
#pragma unroll
    for (int m = 1; m <= 4; m <<= 1) {
      float om = __shfl_xor(m1, m, 64);
      int oi = __shfl_xor(i1, m, 64);
      bool take = (om > m1) || (om == m1 && oi < i1);
      m1 = take ? om : m1;
      i1 = take ? oi : i1;
    }
    // second: exclude argmax, reduce again
    float s1 = (myE == i1) ? -1e30f : logit; int j1 = myE;
#pragma unroll
    for (int m = 1; m <= 4; m <<= 1) {
      float om = __shfl_xor(s1, m, 64);
      int oi = __shfl_xor(j1, m, 64);
      bool take = (om > s1) || (om == s1 && oi < j1);
      s1 = take ? om : s1;
      j1 = take ? oi : j1;
    }

    if (lane == 0) {
      tokE[token * 2 + 0] = i1;
      tokE[token * 2 + 1] = j1;
    }
    conf += m1;
  }

  __shared__ float cf[4];
  if (lane == 0) cf[wave] = conf;
  __syncthreads();
  if (threadIdx.x == 0) confPart[blockIdx.x] = cf[0] + cf[1] + cf[2] + cf[3];
}

// ---------------- K2: per-chunk (256 tokens) expert counts ----------------
__global__ void k_count(const int* __restrict__ tokE, int* __restrict__ chunkCnt) {
  __shared__ int c[E];
  if (threadIdx.x < E) c[threadIdx.x] = 0;
  __syncthreads();
  int token = blockIdx.x * 256 + threadIdx.x;
  atomicAdd(&c[tokE[token * 2 + 0]], 1);
  atomicAdd(&c[tokE[token * 2 + 1]], 1);
  __syncthreads();
  if (threadIdx.x < E) chunkCnt[blockIdx.x * E + threadIdx.x] = c[threadIdx.x];
}

// ---------------- K3: wave-parallel scan (512 thr, wave e = expert e) + stats ----------------
__global__ void k_scan(const int* __restrict__ chunkCnt, const float* __restrict__ confPart,
                       int* __restrict__ chunkOff, int* __restrict__ kept,
                       float* __restrict__ outTail, int nConf, int cap, int nTok) {
  const int lane = threadIdx.x & 63;
  const int e = threadIdx.x >> 6;         // 8 waves, one per expert (nChunks == 128)
  __shared__ int keptS[E];

  int v0 = chunkCnt[lane * E + e];
  int v1 = chunkCnt[(64 + lane) * E + e];
  int s0 = v0, s1 = v1;
#pragma unroll
  for (int off = 1; off < 64; off <<= 1) {
    int t0 = __shfl_up(s0, off, 64);
    int t1 = __shfl_up(s1, off, 64);
    if (lane >= off) { s0 += t0; s1 += t1; }
  }
  int tot0 = __shfl(s0, 63, 64);
  int total = tot0 + __shfl(s1, 63, 64);
  chunkOff[lane * E + e] = s0 - v0;
  chunkOff[(64 + lane) * E + e] = tot0 + s1 - v1;
  if (lane == 0) {
    int k = min(total, cap);
    kept[e] = k;
    keptS[e] = k;
  }

  __shared__ float s[512];
  float a = 0.f;
  for (int i = threadIdx.x; i < nConf; i += 512) a += confPart[i];
  s[threadIdx.x] = a;
  __syncthreads();
  for (int st = 256; st > 0; st >>= 1) {
    if (threadIdx.x < st) s[threadIdx.x] += s[threadIdx.x + st];
    __syncthreads();
  }
  if (threadIdx.x == 0) {
    float tot = 0.f, ld[E];
    for (int i = 0; i < E; ++i) { ld[i] = (float)keptS[i]; tot += ld[i]; }
    float denom = tot + 1e-8f;
    float loss = 0.f;
    for (int i = 0; i < E; ++i) {
      float dist = ld[i] / denom;
      loss += dist * logf(dist + 1e-8f);
      outTail[1 + i] = dist;
    }
    outTail[0] = loss;
    outTail[1 + E] = s[0] / (float)nTok;
  }
}

// ---------------- K4: rank assignment + dispatch lists + token->slot map ----------------
__global__ void k_dispatch(const int* __restrict__ tokE, const int* __restrict__ chunkOff,
                           int* __restrict__ expList, int2* __restrict__ tokSlot, int cap) {
  const int lane = threadIdx.x & 63;
  const int wave = threadIdx.x >> 6;
  const int token = blockIdx.x * 256 + threadIdx.x;
  const int e0 = tokE[token * 2 + 0];
  const int e1 = tokE[token * 2 + 1];
  __shared__ int wcnt[4][E];
  unsigned long long lt = (lane == 63) ? 0x7fffffffffffffffull : ((1ull << lane) - 1ull);
  int r0 = 0, r1 = 0;
#pragma unroll
  for (int e = 0; e < E; ++e) {
    unsigned long long b0 = __ballot(e0 == e);
    unsigned long long b1 = __ballot(e1 == e);
    unsigned long long m = b0 | b1;
    if (e0 == e) r0 = __popcll(m & lt);
    if (e1 == e) r1 = __popcll(m & lt);
    if (lane == 0) wcnt[wave][e] = __popcll(m);
  }
  __syncthreads();
  int base0 = chunkOff[blockIdx.x * E + e0];
  int base1 = chunkOff[blockIdx.x * E + e1];
  for (int w = 0; w < wave; ++w) {
    base0 += wcnt[w][e0];
    base1 += wcnt[w][e1];
  }
  int g0 = base0 + r0;
  int g1 = base1 + r1;
  if (g0 < cap) expList[e0 * cap + g0] = token;
  if (g1 < cap) expList[e1 * cap + g1] = token;
  tokSlot[token] = make_int2(g0 < cap ? e0 * cap + g0 : -1,
                             g1 < cap ? e1 * cap + g1 : -1);
}

// ---------------- K5: per-expert FFN via MFMA, fragment-contiguous weights ----------------
template <bool USE_XB>
__global__ __launch_bounds__(256, 1) void k_expert_mfma(
    const short* __restrict__ xb, const float* __restrict__ x,
    const short* __restrict__ W1f, const float* __restrict__ b1,
    const short* __restrict__ W2f, const float* __restrict__ b2,
    const int* __restrict__ expList, const int* __restrict__ kept,
    short* __restrict__ yscr, int cap) {
  const int e = blockIdx.y;
  const int cnt = kept[e];
  const int t0 = blockIdx.x * BM;
  if (t0 >= cnt) return;
  const int lane = threadIdx.x & 63;
  const int wave = threadIdx.x >> 6;
  const int rb = wave * 16;
  const int n15 = lane & 15;
  const int grp = lane >> 4;
  const int kg = grp * 8;

  __shared__ int toks[BM];
  __shared__ short hs[BM][HP];

  if (threadIdx.x < BM) {
    int idx = min(t0 + (int)threadIdx.x, cnt - 1);
    toks[threadIdx.x] = expList[e * cap + idx];
  }
  __syncthreads();

  short8v xf[16];
  if (USE_XB) {
    const short* xrow = xb + (size_t)toks[rb + n15] * D + kg;
#pragma unroll
    for (int ks = 0; ks < 16; ++ks)
      xf[ks] = *(const short8v*)(xrow + ks * 32);
  } else {
    const float* xrow = x + (size_t)toks[rb + n15] * D + kg;
#pragma unroll
    for (int ks = 0; ks < 16; ++ks) {
      float4 a = *(const float4*)(xrow + ks * 32);
      float4 b = *(const float4*)(xrow + ks * 32 + 4);
      short8v f;
      f[0] = f2bf(a.x); f[1] = f2bf(a.y); f[2] = f2bf(a.z); f[3] = f2bf(a.w);
      f[4] = f2bf(b.x); f[5] = f2bf(b.y); f[6] = f2bf(b.z); f[7] = f2bf(b.w);
      xf[ks] = f;
    }
  }

  const short* w1 = W1f + ((size_t)e * 128 * 64 + lane) * 8;
  float4v acc[8];
#pragma unroll
  for (int t = 0; t < 8; ++t) acc[t] = (float4v){0.f, 0.f, 0.f, 0.f};
#pragma unroll
  for (int ks = 0; ks < 16; ++ks) {
    short8v wf[8];
#pragma unroll
    for (int t = 0; t < 8; ++t)
      wf[t] = *(const short8v*)(w1 + (size_t)(ks * 8 + t) * 64 * 8);
#pragma unroll
    for (int t = 0; t < 8; ++t)
      acc[t] = __builtin_amdgcn_mfma_f32_16x16x32_bf16(wf[t], xf[ks], acc[t], 0, 0, 0);
  }
#pragma unroll
  for (int t = 0; t < 8; ++t) {
    float4 bb = *(const float4*)(b1 + e * H + t * 16 + grp * 4);
    short4v p;
    p[0] = f2bf(fmaxf(acc[t][0] + bb.x, 0.f));
    p[1] = f2bf(fmaxf(acc[t][1] + bb.y, 0.f));
    p[2] = f2bf(fmaxf(acc[t][2] + bb.z, 0.f));
    p[3] = f2bf(fmaxf(acc[t][3] + bb.w, 0.f));
    *(short4v*)(&hs[rb + n15][t * 16 + grp * 4]) = p;
  }
  __syncthreads();

  short8v a4[4];
#pragma unroll
  for (int ks = 0; ks < 4; ++ks)
    a4[ks] = *(const short8v*)(&hs[rb + n15][ks * 32 + kg]);

  const short* w2 = W2f + ((size_t)e * 128 * 64 + lane) * 8;
  short* yrow = yscr + ((size_t)(e * cap + t0 + rb + n15)) * D;
#pragma unroll 4
  for (int t = 0; t < 32; ++t) {
    short8v wf[4];
#pragma unroll
    for (int ks = 0; ks < 4; ++ks)
      wf[ks] = *(const short8v*)(w2 + (size_t)(ks * 32 + t) * 64 * 8);
    float4v y = (float4v){0.f, 0.f, 0.f, 0.f};
#pragma unroll
    for (int ks = 0; ks < 4; ++ks)
      y = __builtin_amdgcn_mfma_f32_16x16x32_bf16(wf[ks], a4[ks], y, 0, 0, 0);
    float4 bb = *(const float4*)(b2 + e * D + t * 16 + grp * 4);
    short4v p;
    p[0] = f2bf(y[0] + bb.x);
    p[1] = f2bf(y[1] + bb.y);
    p[2] = f2bf(y[2] + bb.z);
    p[3] = f2bf(y[3] + bb.w);
    *(short4v*)(yrow + t * 16 + grp * 4) = p;
  }
}

// ---------------- K6: combine — out[token] = sum of kept slots (or 0) ----------------
__global__ void k_combine(const short* __restrict__ yscr, const int2* __restrict__ tokSlot,
                          float* __restrict__ out) {
  const int idx = blockIdx.x * 256 + threadIdx.x;
  const int token = idx >> 7;
  const int c4 = idx & 127;
  int2 sl = tokSlot[token];
  float4 r = make_float4(0.f, 0.f, 0.f, 0.f);
  if (sl.x >= 0) {
    short4v y = *(const short4v*)(yscr + (size_t)sl.x * D + c4 * 4);
    r.x += bf2f(y[0]); r.y += bf2f(y[1]); r.z += bf2f(y[2]); r.w += bf2f(y[3]);
  }
  if (sl.y >= 0) {
    short4v y = *(const short4v*)(yscr + (size_t)sl.y * D + c4 * 4);
    r.x += bf2f(y[0]); r.y += bf2f(y[1]); r.z += bf2f(y[2]); r.w += bf2f(y[3]);
  }
  reinterpret_cast<float4*>(out)[idx] = r;
}

extern "C" void kernel_launch(void* const* d_in, const int* in_sizes, int n_in,
                              void* d_out, int out_size, void* d_ws, size_t ws_size,
                              hipStream_t stream) {
  const float* x  = (const float*)d_in[0];
  const float* Wr = (const float*)d_in[1];
  const float* br = (const float*)d_in[2];
  const float* W1 = (const float*)d_in[3];
  const float* b1 = (const float*)d_in[4];
  const float* W2 = (const float*)d_in[5];
  const float* b2 = (const float*)d_in[6];
  float* out = (float*)d_out;

  const int N = in_sizes[0] / D;                 // 32768
  const int cap = (int)(1.25f * (float)(N / E)); // 5120
  const int chunks = N / 256;                    // 128
  const int rblocks = N / (4 * RT);              // 512 router blocks

  int* tokE = (int*)d_ws;                                    // N*2
  float* confPart = (float*)(tokE + (size_t)N * 2);          // rblocks
  int* chunkCnt = (int*)(confPart + rblocks);                // chunks*E
  int* chunkOff = chunkCnt + chunks * E;                     // chunks*E
  int* kept = chunkOff + chunks * E;                         // E
  int2* tokSlot = (int2*)(kept + E);                         // N int2
  int* expList = (int*)(tokSlot + N);                        // E*cap
  short* W1f = (short*)(expList + (size_t)E * cap);          // [E][128][64][8]
  short* W2f = W1f + (size_t)E * H * D;                      // [E][128][64][8]
  short* yscr = W2f + (size_t)E * H * D;                     // [E*cap][D] bf16
  short* xb = yscr + (size_t)E * cap * D;                    // [N][D] bf16 (optional)

  const size_t needed = (size_t)((char*)(xb + (size_t)N * D) - (char*)d_ws);
  const bool useXB = ws_size >= needed;

  k_swizzle<<<dim3(32, E), 256, 0, stream>>>(W1, W2, W1f, W2f);

  k_router<<<rblocks, 256, 0, stream>>>(x, Wr, br, tokE, confPart,
                                        useXB ? xb : nullptr);
  k_count<<<chunks, 256, 0, stream>>>(tokE, chunkCnt);
  k_scan<<<1, 512, 0, stream>>>(chunkCnt, confPart, chunkOff, kept,
                                out + (size_t)N * D, rblocks, cap, N);
  k_dispatch<<<chunks, 256, 0, stream>>>(tokE, chunkOff, expList, tokSlot, cap);

  const int tiles = (cap + BM - 1) / BM;
  dim3 g5(tiles, E);
  if (useXB)
    k_expert_mfma<true><<<g5, 256, 0, stream>>>(xb, x, W1f, b1, W2f, b2,
                                                expList, kept, yscr, cap);
  else
    k_expert_mfma<false><<<g5, 256, 0, stream>>>(nullptr, x, W1f, b1, W2f, b2,
                                                 expList, kept, yscr, cap);

  k_combine<<<(N * D / 4) / 256, 256, 0, stream>>>(yscr, tokSlot, out);
}